// Round 8
// baseline (69.797 us; speedup 1.0000x reference)
//
#include <hip/hip_runtime.h>
#include <math.h>

// Layout: sample = 16 lanes x 16 slots; 1 sample per 16-lane group.
// State stored as 32 scalar floats re[16], im[16]; state index u = ll*16 + r,
// qubit q <-> bit (7-q) of u (lane bits 7..4 = ll bits 3..0; slot bits 3..0 = r).
//
// CNOT rings are NEVER materialized (constexpr GF(2) basis maps P1..P4);
// Rot = Rz·Ry·Rz with Rz's merged into per-layer diagonals (LDS tables) and
// Ry's applied as generalized butterflies with constexpr masks/duals.
// ALL cross-lane xors are pure DPP (<=2 ops): xor8=row_ror:8, xor7=half_mirror,
// xor15=mirror, xor1/2/3=quad_perm, others composed. Zero ds_swizzle.

typedef float v2f __attribute__((ext_vector_type(2)));

// ---------------- constexpr GF(2) machinery ----------------
struct M8 { unsigned char r[8]; };   // t_b = parity(r[b] & u)

constexpr M8 ident8() {
    M8 m{};
    for (int b = 0; b < 8; ++b) m.r[b] = (unsigned char)(1u << b);
    return m;
}
constexpr M8 ring_mat(M8 m, int s) {
    for (int i = 0; i < 8; ++i) {
        const int cb = 7 - i, tb = 7 - ((i + s) & 7);
        m.r[tb] = (unsigned char)(m.r[tb] ^ m.r[cb]);
    }
    return m;
}
constexpr M8 inv8(M8 a) {
    M8 inv = ident8();
    for (int col = 0; col < 8; ++col) {
        int piv = col;
        while (!((a.r[piv] >> col) & 1)) ++piv;
        unsigned char t = a.r[piv]; a.r[piv] = a.r[col]; a.r[col] = t;
        t = inv.r[piv]; inv.r[piv] = inv.r[col]; inv.r[col] = t;
        for (int q = 0; q < 8; ++q)
            if (q != col && ((a.r[q] >> col) & 1)) {
                a.r[q] = (unsigned char)(a.r[q] ^ a.r[col]);
                inv.r[q] = (unsigned char)(inv.r[q] ^ inv.r[col]);
            }
    }
    return inv;
}
constexpr int mask_of(M8 inv, int b) {   // P^{-1} e_b
    int m = 0;
    for (int j = 0; j < 8; ++j) m |= ((inv.r[j] >> b) & 1) << j;
    return m;
}

constexpr M8 P1c  = ring_mat(ident8(), 1);
constexpr M8 P2c  = ring_mat(P1c, 2);
constexpr M8 P3c  = ring_mat(P2c, 3);
constexpr M8 P4c  = ring_mat(P3c, 4);
constexpr M8 P1ic = inv8(P1c);
constexpr M8 P2ic = inv8(P2c);
constexpr M8 P3ic = inv8(P3c);

// ---------------- cross-lane xor within 16-lane rows: PURE DPP ----------------
template<int CTRL>
__device__ __forceinline__ float dppf(float v) {
    const int i = __float_as_int(v);
    return __int_as_float(__builtin_amdgcn_update_dpp(i, i, CTRL, 0xF, 0xF, true));
}
template<int M>
__device__ __forceinline__ float lxorf(float v) {
    static_assert(M >= 1 && M <= 15, "bad mask");
    if constexpr (M == 1)       return dppf<0xB1>(v);    // quad_perm [1,0,3,2]
    else if constexpr (M == 2)  return dppf<0x4E>(v);    // quad_perm [2,3,0,1]
    else if constexpr (M == 3)  return dppf<0x1B>(v);    // quad_perm [3,2,1,0]
    else if constexpr (M == 7)  return dppf<0x141>(v);   // row_half_mirror: l^7
    else if constexpr (M == 8)  return dppf<0x128>(v);   // row_ror:8: l^8
    else if constexpr (M == 15) return dppf<0x140>(v);   // row_mirror: l^15
    else if constexpr (M < 7)   return lxorf<7>(lxorf<M ^ 7>(v));    // 4,5,6
    else if constexpr (M < 12)  return lxorf<8>(lxorf<M ^ 8>(v));    // 9,10,11
    else                        return lxorf<15>(lxorf<M ^ 15>(v));  // 12,13,14
}

// ---------------- generalized Ry gate ----------------
template<int MASK, int DUAL>
__device__ __forceinline__ void gry(float (&re)[16], float (&im)[16], int ll, v2f cs)
{
    constexpr int ml = (MASK >> 4) & 15, ms = MASK & 15;
    constexpr int dl = (DUAL >> 4) & 15, ds = DUAL & 15;
    const float c = cs.x, s = cs.y;
    float tp;
    if constexpr (dl != 0) {
        int t = ll & dl; t ^= t >> 2; t ^= t >> 1;
        tp = (t & 1) ? s : -s;      // coef where parity(r&ds)==0
    } else {
        tp = -s;
    }
    const float tn = -tp;
    if constexpr (ms == 0) {
        #pragma unroll
        for (int r = 0; r < 16; ++r) {
            int pp = r & ds; pp ^= pp >> 2; pp ^= pp >> 1;     // folds (r literal)
            const float tr = (pp & 1) ? tn : tp;
            re[r] = fmaf(tr, lxorf<ml>(re[r]), c * re[r]);
            im[r] = fmaf(tr, lxorf<ml>(im[r]), c * im[r]);
        }
    } else {
        constexpr int lo = ms & (-ms);
        #pragma unroll
        for (int r0 = 0; r0 < 16; ++r0) {
            if ((r0 & lo) == 0) {
                const int r1 = r0 ^ ms;
                int p0 = r0 & ds; p0 ^= p0 >> 2; p0 ^= p0 >> 1;
                int p1 = r1 & ds; p1 ^= p1 >> 2; p1 ^= p1 >> 1;
                const float t0 = (p0 & 1) ? tn : tp;
                const float t1 = (p1 & 1) ? tn : tp;
                float q0r, q0i, q1r, q1i;
                if constexpr (ml != 0) {
                    q0r = lxorf<ml>(re[r1]); q0i = lxorf<ml>(im[r1]);
                    q1r = lxorf<ml>(re[r0]); q1i = lxorf<ml>(im[r0]);
                } else {
                    q0r = re[r1]; q0i = im[r1];
                    q1r = re[r0]; q1i = im[r0];
                }
                const float n0r = fmaf(t0, q0r, c * re[r0]);
                const float n0i = fmaf(t0, q0i, c * im[r0]);
                const float n1r = fmaf(t1, q1r, c * re[r1]);
                const float n1i = fmaf(t1, q1i, c * im[r1]);
                re[r0] = n0r; im[r0] = n0i;
                re[r1] = n1r; im[r1] = n1i;
            }
        }
    }
}

template<int L>   // L = 1,2,3
__device__ __forceinline__ void gry_layer(float (&re)[16], float (&im)[16], int ll,
                                          const v2f* __restrict__ cs)
{
    constexpr M8 P  = (L == 1) ? P1c  : (L == 2) ? P2c  : P3c;
    constexpr M8 Pi = (L == 1) ? P1ic : (L == 2) ? P2ic : P3ic;
    gry<mask_of(Pi, 7), P.r[7]>(re, im, ll, cs[0]);   // qubit 0
    gry<mask_of(Pi, 6), P.r[6]>(re, im, ll, cs[1]);
    gry<mask_of(Pi, 5), P.r[5]>(re, im, ll, cs[2]);
    gry<mask_of(Pi, 4), P.r[4]>(re, im, ll, cs[3]);
    gry<mask_of(Pi, 3), P.r[3]>(re, im, ll, cs[4]);
    gry<mask_of(Pi, 2), P.r[2]>(re, im, ll, cs[5]);
    gry<mask_of(Pi, 1), P.r[1]>(re, im, ll, cs[6]);
    gry<mask_of(Pi, 0), P.r[0]>(re, im, ll, cs[7]);   // qubit 7
}

// ---------------- diagonal apply (interleaved re,im; row stride 36 floats) ----------------
__device__ __forceinline__ void diag_apply(float (&re)[16], float (&im)[16],
                                           const float* __restrict__ tab, int ll)
{
    const float4* p4 = reinterpret_cast<const float4*>(tab + ll * 36);
    #pragma unroll
    for (int j = 0; j < 8; ++j) {
        const float4 v = p4[j];           // (re0,im0,re1,im1) for slots 2j,2j+1
        const int r0 = 2 * j, r1 = 2 * j + 1;
        float nr = v.x * re[r0] - v.y * im[r0];
        float ni = v.x * im[r0] + v.y * re[r0];
        re[r0] = nr; im[r0] = ni;
        nr = v.z * re[r1] - v.w * im[r1];
        ni = v.z * im[r1] + v.w * re[r1];
        re[r1] = nr; im[r1] = ni;
    }
}

// ---- init: product state (Rot_layer0_i · RX(x_i)) |0> (round-3/6-verified math) ----
__device__ __forceinline__ void init_state(const float* __restrict__ xp,
                                           const v2f (*Gc)[4], int ll,
                                           float (&re)[16], float (&im)[16])
{
    const float4 xv0 = *reinterpret_cast<const float4*>(xp);
    const float4 xv1 = *reinterpret_cast<const float4*>(xp + 4);
    const float xs[8] = {xv0.x, xv0.y, xv0.z, xv0.w, xv1.x, xv1.y, xv1.z, xv1.w};
    const int b0 = (ll >> 3) & 1, b1_ = (ll >> 2) & 1, b2_ = (ll >> 1) & 1, b3 = ll & 1;

    v2f w0v[8], w1v[8];
    #pragma unroll
    for (int i = 0; i < 8; ++i) {
        float sx, cx;
        __sincosf(0.5f * xs[i], &sx, &cx);
        const v2f m00 = Gc[i][0], m01 = Gc[i][1], m10 = Gc[i][2], m11 = Gc[i][3];
        w0v[i].x = fmaf(cx, m00.x,  sx * m01.y);
        w0v[i].y = fmaf(cx, m00.y, -(sx * m01.x));
        w1v[i].x = fmaf(cx, m10.x,  sx * m11.y);
        w1v[i].y = fmaf(cx, m10.y, -(sx * m11.x));
    }

    v2f L = b0 ? w1v[0] : w0v[0];
    {
        const v2f f = b1_ ? w1v[1] : w0v[1];
        v2f t; t.x = fmaf(L.x, f.x, -(L.y * f.y)); t.y = fmaf(L.x, f.y, L.y * f.x); L = t;
    }
    {
        const v2f f = b2_ ? w1v[2] : w0v[2];
        v2f t; t.x = fmaf(L.x, f.x, -(L.y * f.y)); t.y = fmaf(L.x, f.y, L.y * f.x); L = t;
    }
    {
        const v2f f = b3 ? w1v[3] : w0v[3];
        v2f t; t.x = fmaf(L.x, f.x, -(L.y * f.y)); t.y = fmaf(L.x, f.y, L.y * f.x); L = t;
    }

    v2f p45[4], p67[4];
    #pragma unroll
    for (int a = 0; a < 4; ++a) {
        const int bh = (a >> 1) & 1, bl = a & 1;
        const v2f u = bh ? w1v[4] : w0v[4], v = bl ? w1v[5] : w0v[5];
        p45[a].x = fmaf(u.x, v.x, -(u.y * v.y)); p45[a].y = fmaf(u.x, v.y, u.y * v.x);
        const v2f u2 = bh ? w1v[6] : w0v[6], v2_ = bl ? w1v[7] : w0v[7];
        p67[a].x = fmaf(u2.x, v2_.x, -(u2.y * v2_.y)); p67[a].y = fmaf(u2.x, v2_.y, u2.y * v2_.x);
    }
    v2f L45[4];
    #pragma unroll
    for (int a = 0; a < 4; ++a) {
        L45[a].x = fmaf(L.x, p45[a].x, -(L.y * p45[a].y));
        L45[a].y = fmaf(L.x, p45[a].y,   L.y * p45[a].x);
    }
    #pragma unroll
    for (int r = 0; r < 16; ++r) {
        const int a = r >> 2, b = r & 3;
        re[r] = fmaf(L45[a].x, p67[b].x, -(L45[a].y * p67[b].y));
        im[r] = fmaf(L45[a].x, p67[b].y,   L45[a].y * p67[b].x);
    }
}

// ---- signed lane sum: returns sum_l (-1)^{parity(l&DL)} x_l at all lanes ----
template<int DL>
__device__ __forceinline__ float lane_wht(float v, int ll)
{
    if constexpr ((DL & 1) == 0) v += lxorf<1>(v); else v -= lxorf<1>(v);
    if constexpr ((DL & 2) == 0) v += lxorf<2>(v); else v -= lxorf<2>(v);
    if constexpr ((DL & 4) == 0) v += lxorf<4>(v); else v -= lxorf<4>(v);
    if constexpr ((DL & 8) == 0) v += lxorf<8>(v); else v -= lxorf<8>(v);
    if constexpr (DL != 0) {
        int t = ll & DL; t ^= t >> 2; t ^= t >> 1;
        v = (t & 1) ? -v : v;
    }
    return v;
}

// dot of angle-halves with sign pattern from bits of t (qubit i <-> bit 7-i)
__device__ __forceinline__ float dotang(const float* __restrict__ w, int t)
{
    float a = 0.f;
    #pragma unroll
    for (int i = 0; i < 8; ++i) {
        const float h = 0.5f * w[i * 3];
        a += ((t >> (7 - i)) & 1) ? h : -h;
    }
    return a;
}
__device__ __forceinline__ int applyP(M8 m, int u)
{
    int t = 0;
    #pragma unroll
    for (int b = 0; b < 8; ++b)
        t |= (__builtin_popcount((int)m.r[b] & u) & 1) << b;
    return t;
}

__global__ void __launch_bounds__(256)
qae_fused(const float* __restrict__ x, const float* __restrict__ qw,
          const float* __restrict__ w1, const float* __restrict__ b1,
          const float* __restrict__ w2, const float* __restrict__ b2,
          float* __restrict__ out, int nsamp)
{
    __shared__ __align__(16) float dA[16 * 36];
    __shared__ __align__(16) float dB[16 * 36];
    __shared__ __align__(16) float dC[16 * 36];
    __shared__ __align__(16) v2f Gc[8][4];    // layer-0 Rot matrices (init)
    __shared__ v2f RyCS[24];                  // (cos(th/2), sin(th/2)) layers 1..3

    const int tid = threadIdx.x;
    const int u = tid;

    // --- preamble: diag tables in the STORAGE basis via constexpr maps ---
    {
        const int t1 = applyP(P1c, u);
        const int t2 = applyP(P2c, u);
        const int t3 = applyP(P3c, u);
        const float aA = dotang(qw + 24 + 0, t1);                              // phi1
        const float aB = dotang(qw + 24 + 2, t1) + dotang(qw + 48 + 0, t2);    // om1+phi2
        const float aC = dotang(qw + 48 + 2, t2) + dotang(qw + 72 + 0, t3);    // om2+phi3
        const int row = u >> 4, col = u & 15;
        const int idx = row * 36 + col * 2;
        float s_, c_;
        sincosf(aA, &s_, &c_); dA[idx] = c_; dA[idx + 1] = s_;
        sincosf(aB, &s_, &c_); dB[idx] = c_; dB[idx + 1] = s_;
        sincosf(aC, &s_, &c_); dC[idx] = c_; dC[idx + 1] = s_;
    }
    if (tid < 24) {                      // Ry constants, layers 1..3
        const int l = 1 + (tid >> 3), i = tid & 7;
        float s_, c_;
        sincosf(0.5f * qw[l * 24 + i * 3 + 1], &s_, &c_);
        v2f t; t.x = c_; t.y = s_;
        RyCS[tid] = t;
    }
    if (tid >= 32 && tid < 40) {         // layer-0 Rot matrices for init
        const int i = tid - 32;
        const float phi = qw[i * 3 + 0], th = qw[i * 3 + 1], om = qw[i * 3 + 2];
        float s, c, sp, cp, sm, cm;
        sincosf(0.5f * th,         &s,  &c);
        sincosf(0.5f * (phi + om), &sp, &cp);
        sincosf(0.5f * (phi - om), &sm, &cm);
        v2f t;
        t.x =  cp * c; t.y = -sp * c; Gc[i][0] = t;   // m00
        t.x = -cm * s; t.y = -sm * s; Gc[i][1] = t;   // m01
        t.x =  cm * s; t.y = -sm * s; Gc[i][2] = t;   // m10
        t.x =  cp * c; t.y =  sp * c; Gc[i][3] = t;   // m11
    }
    __syncthreads();

    const int sample = (blockIdx.x * 256 + tid) >> 4;
    if (sample >= nsamp) return;
    const int ll = tid & 15;

    float re[16], im[16];
    init_state(x + (size_t)sample * 8, Gc, ll, re, im);

    // layer 1..3: diag then generalized-Ry (rings live only in the constexpr maps)
    diag_apply(re, im, dA, ll);
    gry_layer<1>(re, im, ll, RyCS);
    diag_apply(re, im, dB, ll);
    gry_layer<2>(re, im, ll, RyCS + 8);
    diag_apply(re, im, dC, ll);
    gry_layer<3>(re, im, ll, RyCS + 16);
    // omega3 dropped (|.|^2 readout); ring4 folded into P4 readout duals

    // --- readout: slot FWHT + signed lane butterflies with duals = rows of P4 ---
    float W[16];
    #pragma unroll
    for (int r = 0; r < 16; ++r) W[r] = fmaf(re[r], re[r], im[r] * im[r]);
    #pragma unroll
    for (int b = 0; b < 4; ++b) {
        const int m = 1 << b;
        #pragma unroll
        for (int r = 0; r < 16; ++r) {
            if (!(r & m)) {
                const float a = W[r], bb = W[r ^ m];
                W[r] = a + bb; W[r ^ m] = a - bb;
            }
        }
    }
    float z[8];
    z[0] = lane_wht<(P4c.r[7] >> 4)>(W[P4c.r[7] & 15], ll);
    z[1] = lane_wht<(P4c.r[6] >> 4)>(W[P4c.r[6] & 15], ll);
    z[2] = lane_wht<(P4c.r[5] >> 4)>(W[P4c.r[5] & 15], ll);
    z[3] = lane_wht<(P4c.r[4] >> 4)>(W[P4c.r[4] & 15], ll);
    z[4] = lane_wht<(P4c.r[3] >> 4)>(W[P4c.r[3] & 15], ll);
    z[5] = lane_wht<(P4c.r[2] >> 4)>(W[P4c.r[2] & 15], ll);
    z[6] = lane_wht<(P4c.r[1] >> 4)>(W[P4c.r[1] & 15], ll);
    z[7] = lane_wht<(P4c.r[0] >> 4)>(W[P4c.r[0] & 15], ll);

    // --- MLP: out = w2 · relu(w1 · z + b1) + b2 ---
    if (ll < 8) {
        float h0 = b1[0], h1 = b1[1], h2 = b1[2], h3 = b1[3];
        #pragma unroll
        for (int i = 0; i < 8; ++i) {
            h0 += z[i] * w1[i];
            h1 += z[i] * w1[8 + i];
            h2 += z[i] * w1[16 + i];
            h3 += z[i] * w1[24 + i];
        }
        h0 = fmaxf(h0, 0.f); h1 = fmaxf(h1, 0.f);
        h2 = fmaxf(h2, 0.f); h3 = fmaxf(h3, 0.f);
        const float o = b2[ll] + h0 * w2[ll * 4 + 0] + h1 * w2[ll * 4 + 1]
                                + h2 * w2[ll * 4 + 2] + h3 * w2[ll * 4 + 3];
        out[(size_t)sample * 8 + ll] = o;
    }
}

extern "C" void kernel_launch(void* const* d_in, const int* in_sizes, int n_in,
                              void* d_out, int out_size, void* d_ws, size_t ws_size,
                              hipStream_t stream)
{
    const float* x  = (const float*)d_in[0];
    const float* qw = (const float*)d_in[1];
    const float* w1 = (const float*)d_in[2];
    const float* b1 = (const float*)d_in[3];
    const float* w2 = (const float*)d_in[4];
    const float* b2 = (const float*)d_in[5];
    float* out = (float*)d_out;

    const int nsamp = in_sizes[0] / 8;              // 65536
    const int total_threads = nsamp * 16;           // 16 lanes per sample
    const int blocks = (total_threads + 255) / 256; // 4096

    hipLaunchKernelGGL(qae_fused, dim3(blocks), dim3(256), 0, stream,
                       x, qw, w1, b1, w2, b2, out, nsamp);
}

// Round 9
// 61.422 us; speedup vs baseline: 1.1363x; 1.1363x over previous
//
#include <hip/hip_runtime.h>
#include <math.h>

// Layout: sample = 16 lanes x 16 slots; 1 sample per 16-lane group.
// State stored as 32 scalar floats re[16], im[16]; state index u = ll*16 + r,
// qubit q <-> bit (7-q) of u (lane bits 7..4 = ll bits 3..0; slot bits 3..0 = r).
//
// CNOT rings are NEVER materialized (constexpr GF(2) basis maps P1..P4);
// Rot = Rz·Ry·Rz with Rz's merged into per-layer diagonals (LDS tables) and
// Ry's applied as generalized butterflies with constexpr masks/duals.
// Cross-lane xor pipe balance (R7 vs R8 measured): single-op DPP for masks
// {1,2,3,7,8,15} (VALU pipe), single ds_swizzle for composite masks
// {4,5,6,9,10,11,12,13,14} (LDS pipe, overlaps with VALU).

typedef float v2f __attribute__((ext_vector_type(2)));

// ---------------- constexpr GF(2) machinery ----------------
struct M8 { unsigned char r[8]; };   // t_b = parity(r[b] & u)

constexpr M8 ident8() {
    M8 m{};
    for (int b = 0; b < 8; ++b) m.r[b] = (unsigned char)(1u << b);
    return m;
}
constexpr M8 ring_mat(M8 m, int s) {
    for (int i = 0; i < 8; ++i) {
        const int cb = 7 - i, tb = 7 - ((i + s) & 7);
        m.r[tb] = (unsigned char)(m.r[tb] ^ m.r[cb]);
    }
    return m;
}
constexpr M8 inv8(M8 a) {
    M8 inv = ident8();
    for (int col = 0; col < 8; ++col) {
        int piv = col;
        while (!((a.r[piv] >> col) & 1)) ++piv;
        unsigned char t = a.r[piv]; a.r[piv] = a.r[col]; a.r[col] = t;
        t = inv.r[piv]; inv.r[piv] = inv.r[col]; inv.r[col] = t;
        for (int q = 0; q < 8; ++q)
            if (q != col && ((a.r[q] >> col) & 1)) {
                a.r[q] = (unsigned char)(a.r[q] ^ a.r[col]);
                inv.r[q] = (unsigned char)(inv.r[q] ^ inv.r[col]);
            }
    }
    return inv;
}
constexpr int mask_of(M8 inv, int b) {   // P^{-1} e_b
    int m = 0;
    for (int j = 0; j < 8; ++j) m |= ((inv.r[j] >> b) & 1) << j;
    return m;
}

constexpr M8 P1c  = ring_mat(ident8(), 1);
constexpr M8 P2c  = ring_mat(P1c, 2);
constexpr M8 P3c  = ring_mat(P2c, 3);
constexpr M8 P4c  = ring_mat(P3c, 4);
constexpr M8 P1ic = inv8(P1c);
constexpr M8 P2ic = inv8(P2c);
constexpr M8 P3ic = inv8(P3c);

// ---------------- cross-lane xor within 16-lane rows: pipe-balanced ----------------
template<int CTRL>
__device__ __forceinline__ float dppf(float v) {
    const int i = __float_as_int(v);
    return __int_as_float(__builtin_amdgcn_update_dpp(i, i, CTRL, 0xF, 0xF, true));
}
template<int M>
__device__ __forceinline__ float lxorf(float v) {
    static_assert(M >= 1 && M <= 15, "bad mask");
    if constexpr (M == 1)       return dppf<0xB1>(v);    // quad_perm [1,0,3,2]
    else if constexpr (M == 2)  return dppf<0x4E>(v);    // quad_perm [2,3,0,1]
    else if constexpr (M == 3)  return dppf<0x1B>(v);    // quad_perm [3,2,1,0]
    else if constexpr (M == 7)  return dppf<0x141>(v);   // row_half_mirror: l^7
    else if constexpr (M == 8)  return dppf<0x128>(v);   // row_ror:8: l^8
    else if constexpr (M == 15) return dppf<0x140>(v);   // row_mirror: l^15
    else return __int_as_float(__builtin_amdgcn_ds_swizzle(__float_as_int(v), (M << 10) | 0x1F));
}

// ---------------- generalized Ry gate ----------------
template<int MASK, int DUAL>
__device__ __forceinline__ void gry(float (&re)[16], float (&im)[16], int ll, v2f cs)
{
    constexpr int ml = (MASK >> 4) & 15, ms = MASK & 15;
    constexpr int dl = (DUAL >> 4) & 15, ds = DUAL & 15;
    const float c = cs.x, s = cs.y;
    float tp;
    if constexpr (dl != 0) {
        int t = ll & dl; t ^= t >> 2; t ^= t >> 1;
        tp = (t & 1) ? s : -s;      // coef where parity(r&ds)==0
    } else {
        tp = -s;
    }
    const float tn = -tp;
    if constexpr (ms == 0) {
        #pragma unroll
        for (int r = 0; r < 16; ++r) {
            int pp = r & ds; pp ^= pp >> 2; pp ^= pp >> 1;     // folds (r literal)
            const float tr = (pp & 1) ? tn : tp;
            re[r] = fmaf(tr, lxorf<ml>(re[r]), c * re[r]);
            im[r] = fmaf(tr, lxorf<ml>(im[r]), c * im[r]);
        }
    } else {
        constexpr int lo = ms & (-ms);
        #pragma unroll
        for (int r0 = 0; r0 < 16; ++r0) {
            if ((r0 & lo) == 0) {
                const int r1 = r0 ^ ms;
                int p0 = r0 & ds; p0 ^= p0 >> 2; p0 ^= p0 >> 1;
                int p1 = r1 & ds; p1 ^= p1 >> 2; p1 ^= p1 >> 1;
                const float t0 = (p0 & 1) ? tn : tp;
                const float t1 = (p1 & 1) ? tn : tp;
                float q0r, q0i, q1r, q1i;
                if constexpr (ml != 0) {
                    q0r = lxorf<ml>(re[r1]); q0i = lxorf<ml>(im[r1]);
                    q1r = lxorf<ml>(re[r0]); q1i = lxorf<ml>(im[r0]);
                } else {
                    q0r = re[r1]; q0i = im[r1];
                    q1r = re[r0]; q1i = im[r0];
                }
                const float n0r = fmaf(t0, q0r, c * re[r0]);
                const float n0i = fmaf(t0, q0i, c * im[r0]);
                const float n1r = fmaf(t1, q1r, c * re[r1]);
                const float n1i = fmaf(t1, q1i, c * im[r1]);
                re[r0] = n0r; im[r0] = n0i;
                re[r1] = n1r; im[r1] = n1i;
            }
        }
    }
}

template<int L>   // L = 1,2,3
__device__ __forceinline__ void gry_layer(float (&re)[16], float (&im)[16], int ll,
                                          const v2f* __restrict__ cs)
{
    constexpr M8 P  = (L == 1) ? P1c  : (L == 2) ? P2c  : P3c;
    constexpr M8 Pi = (L == 1) ? P1ic : (L == 2) ? P2ic : P3ic;
    gry<mask_of(Pi, 7), P.r[7]>(re, im, ll, cs[0]);   // qubit 0
    gry<mask_of(Pi, 6), P.r[6]>(re, im, ll, cs[1]);
    gry<mask_of(Pi, 5), P.r[5]>(re, im, ll, cs[2]);
    gry<mask_of(Pi, 4), P.r[4]>(re, im, ll, cs[3]);
    gry<mask_of(Pi, 3), P.r[3]>(re, im, ll, cs[4]);
    gry<mask_of(Pi, 2), P.r[2]>(re, im, ll, cs[5]);
    gry<mask_of(Pi, 1), P.r[1]>(re, im, ll, cs[6]);
    gry<mask_of(Pi, 0), P.r[0]>(re, im, ll, cs[7]);   // qubit 7
}

// ---------------- diagonal apply (interleaved re,im; row stride 36 floats) ----------------
__device__ __forceinline__ void diag_apply(float (&re)[16], float (&im)[16],
                                           const float* __restrict__ tab, int ll)
{
    const float4* p4 = reinterpret_cast<const float4*>(tab + ll * 36);
    #pragma unroll
    for (int j = 0; j < 8; ++j) {
        const float4 v = p4[j];           // (re0,im0,re1,im1) for slots 2j,2j+1
        const int r0 = 2 * j, r1 = 2 * j + 1;
        float nr = v.x * re[r0] - v.y * im[r0];
        float ni = v.x * im[r0] + v.y * re[r0];
        re[r0] = nr; im[r0] = ni;
        nr = v.z * re[r1] - v.w * im[r1];
        ni = v.z * im[r1] + v.w * re[r1];
        re[r1] = nr; im[r1] = ni;
    }
}

// ---- init: product state (Rot_layer0_i · RX(x_i)) |0> (round-3/6-verified math) ----
__device__ __forceinline__ void init_state(const float* __restrict__ xp,
                                           const v2f (*Gc)[4], int ll,
                                           float (&re)[16], float (&im)[16])
{
    const float4 xv0 = *reinterpret_cast<const float4*>(xp);
    const float4 xv1 = *reinterpret_cast<const float4*>(xp + 4);
    const float xs[8] = {xv0.x, xv0.y, xv0.z, xv0.w, xv1.x, xv1.y, xv1.z, xv1.w};
    const int b0 = (ll >> 3) & 1, b1_ = (ll >> 2) & 1, b2_ = (ll >> 1) & 1, b3 = ll & 1;

    v2f w0v[8], w1v[8];
    #pragma unroll
    for (int i = 0; i < 8; ++i) {
        float sx, cx;
        __sincosf(0.5f * xs[i], &sx, &cx);
        const v2f m00 = Gc[i][0], m01 = Gc[i][1], m10 = Gc[i][2], m11 = Gc[i][3];
        w0v[i].x = fmaf(cx, m00.x,  sx * m01.y);
        w0v[i].y = fmaf(cx, m00.y, -(sx * m01.x));
        w1v[i].x = fmaf(cx, m10.x,  sx * m11.y);
        w1v[i].y = fmaf(cx, m10.y, -(sx * m11.x));
    }

    v2f L = b0 ? w1v[0] : w0v[0];
    {
        const v2f f = b1_ ? w1v[1] : w0v[1];
        v2f t; t.x = fmaf(L.x, f.x, -(L.y * f.y)); t.y = fmaf(L.x, f.y, L.y * f.x); L = t;
    }
    {
        const v2f f = b2_ ? w1v[2] : w0v[2];
        v2f t; t.x = fmaf(L.x, f.x, -(L.y * f.y)); t.y = fmaf(L.x, f.y, L.y * f.x); L = t;
    }
    {
        const v2f f = b3 ? w1v[3] : w0v[3];
        v2f t; t.x = fmaf(L.x, f.x, -(L.y * f.y)); t.y = fmaf(L.x, f.y, L.y * f.x); L = t;
    }

    v2f p45[4], p67[4];
    #pragma unroll
    for (int a = 0; a < 4; ++a) {
        const int bh = (a >> 1) & 1, bl = a & 1;
        const v2f u = bh ? w1v[4] : w0v[4], v = bl ? w1v[5] : w0v[5];
        p45[a].x = fmaf(u.x, v.x, -(u.y * v.y)); p45[a].y = fmaf(u.x, v.y, u.y * v.x);
        const v2f u2 = bh ? w1v[6] : w0v[6], v2_ = bl ? w1v[7] : w0v[7];
        p67[a].x = fmaf(u2.x, v2_.x, -(u2.y * v2_.y)); p67[a].y = fmaf(u2.x, v2_.y, u2.y * v2_.x);
    }
    v2f L45[4];
    #pragma unroll
    for (int a = 0; a < 4; ++a) {
        L45[a].x = fmaf(L.x, p45[a].x, -(L.y * p45[a].y));
        L45[a].y = fmaf(L.x, p45[a].y,   L.y * p45[a].x);
    }
    #pragma unroll
    for (int r = 0; r < 16; ++r) {
        const int a = r >> 2, b = r & 3;
        re[r] = fmaf(L45[a].x, p67[b].x, -(L45[a].y * p67[b].y));
        im[r] = fmaf(L45[a].x, p67[b].y,   L45[a].y * p67[b].x);
    }
}

// ---- signed lane sum: returns sum_l (-1)^{parity(l&DL)} x_l at all lanes ----
template<int DL>
__device__ __forceinline__ float lane_wht(float v, int ll)
{
    if constexpr ((DL & 1) == 0) v += lxorf<1>(v); else v -= lxorf<1>(v);
    if constexpr ((DL & 2) == 0) v += lxorf<2>(v); else v -= lxorf<2>(v);
    if constexpr ((DL & 4) == 0) v += lxorf<4>(v); else v -= lxorf<4>(v);
    if constexpr ((DL & 8) == 0) v += lxorf<8>(v); else v -= lxorf<8>(v);
    if constexpr (DL != 0) {
        int t = ll & DL; t ^= t >> 2; t ^= t >> 1;
        v = (t & 1) ? -v : v;
    }
    return v;
}

// dot of angle-halves with sign pattern from bits of t (qubit i <-> bit 7-i)
__device__ __forceinline__ float dotang(const float* __restrict__ w, int t)
{
    float a = 0.f;
    #pragma unroll
    for (int i = 0; i < 8; ++i) {
        const float h = 0.5f * w[i * 3];
        a += ((t >> (7 - i)) & 1) ? h : -h;
    }
    return a;
}
__device__ __forceinline__ int applyP(M8 m, int u)
{
    int t = 0;
    #pragma unroll
    for (int b = 0; b < 8; ++b)
        t |= (__builtin_popcount((int)m.r[b] & u) & 1) << b;
    return t;
}

__global__ void __launch_bounds__(256)
qae_fused(const float* __restrict__ x, const float* __restrict__ qw,
          const float* __restrict__ w1, const float* __restrict__ b1,
          const float* __restrict__ w2, const float* __restrict__ b2,
          float* __restrict__ out, int nsamp)
{
    __shared__ __align__(16) float dA[16 * 36];
    __shared__ __align__(16) float dB[16 * 36];
    __shared__ __align__(16) float dC[16 * 36];
    __shared__ __align__(16) v2f Gc[8][4];    // layer-0 Rot matrices (init)
    __shared__ v2f RyCS[24];                  // (cos(th/2), sin(th/2)) layers 1..3

    const int tid = threadIdx.x;
    const int u = tid;

    // --- preamble: diag tables in the STORAGE basis via constexpr maps ---
    {
        const int t1 = applyP(P1c, u);
        const int t2 = applyP(P2c, u);
        const int t3 = applyP(P3c, u);
        const float aA = dotang(qw + 24 + 0, t1);                              // phi1
        const float aB = dotang(qw + 24 + 2, t1) + dotang(qw + 48 + 0, t2);    // om1+phi2
        const float aC = dotang(qw + 48 + 2, t2) + dotang(qw + 72 + 0, t3);    // om2+phi3
        const int row = u >> 4, col = u & 15;
        const int idx = row * 36 + col * 2;
        float s_, c_;
        __sincosf(aA, &s_, &c_); dA[idx] = c_; dA[idx + 1] = s_;
        __sincosf(aB, &s_, &c_); dB[idx] = c_; dB[idx + 1] = s_;
        __sincosf(aC, &s_, &c_); dC[idx] = c_; dC[idx + 1] = s_;
    }
    if (tid < 24) {                      // Ry constants, layers 1..3
        const int l = 1 + (tid >> 3), i = tid & 7;
        float s_, c_;
        sincosf(0.5f * qw[l * 24 + i * 3 + 1], &s_, &c_);
        v2f t; t.x = c_; t.y = s_;
        RyCS[tid] = t;
    }
    if (tid >= 32 && tid < 40) {         // layer-0 Rot matrices for init
        const int i = tid - 32;
        const float phi = qw[i * 3 + 0], th = qw[i * 3 + 1], om = qw[i * 3 + 2];
        float s, c, sp, cp, sm, cm;
        sincosf(0.5f * th,         &s,  &c);
        sincosf(0.5f * (phi + om), &sp, &cp);
        sincosf(0.5f * (phi - om), &sm, &cm);
        v2f t;
        t.x =  cp * c; t.y = -sp * c; Gc[i][0] = t;   // m00
        t.x = -cm * s; t.y = -sm * s; Gc[i][1] = t;   // m01
        t.x =  cm * s; t.y = -sm * s; Gc[i][2] = t;   // m10
        t.x =  cp * c; t.y =  sp * c; Gc[i][3] = t;   // m11
    }
    __syncthreads();

    const int sample = (blockIdx.x * 256 + tid) >> 4;
    if (sample >= nsamp) return;
    const int ll = tid & 15;

    float re[16], im[16];
    init_state(x + (size_t)sample * 8, Gc, ll, re, im);

    // layer 1..3: diag then generalized-Ry (rings live only in the constexpr maps)
    diag_apply(re, im, dA, ll);
    gry_layer<1>(re, im, ll, RyCS);
    diag_apply(re, im, dB, ll);
    gry_layer<2>(re, im, ll, RyCS + 8);
    diag_apply(re, im, dC, ll);
    gry_layer<3>(re, im, ll, RyCS + 16);
    // omega3 dropped (|.|^2 readout); ring4 folded into P4 readout duals

    // --- readout: slot FWHT + signed lane butterflies with duals = rows of P4 ---
    float W[16];
    #pragma unroll
    for (int r = 0; r < 16; ++r) W[r] = fmaf(re[r], re[r], im[r] * im[r]);
    #pragma unroll
    for (int b = 0; b < 4; ++b) {
        const int m = 1 << b;
        #pragma unroll
        for (int r = 0; r < 16; ++r) {
            if (!(r & m)) {
                const float a = W[r], bb = W[r ^ m];
                W[r] = a + bb; W[r ^ m] = a - bb;
            }
        }
    }
    float z[8];
    z[0] = lane_wht<(P4c.r[7] >> 4)>(W[P4c.r[7] & 15], ll);
    z[1] = lane_wht<(P4c.r[6] >> 4)>(W[P4c.r[6] & 15], ll);
    z[2] = lane_wht<(P4c.r[5] >> 4)>(W[P4c.r[5] & 15], ll);
    z[3] = lane_wht<(P4c.r[4] >> 4)>(W[P4c.r[4] & 15], ll);
    z[4] = lane_wht<(P4c.r[3] >> 4)>(W[P4c.r[3] & 15], ll);
    z[5] = lane_wht<(P4c.r[2] >> 4)>(W[P4c.r[2] & 15], ll);
    z[6] = lane_wht<(P4c.r[1] >> 4)>(W[P4c.r[1] & 15], ll);
    z[7] = lane_wht<(P4c.r[0] >> 4)>(W[P4c.r[0] & 15], ll);

    // --- MLP: out = w2 · relu(w1 · z + b1) + b2 ---
    if (ll < 8) {
        float h0 = b1[0], h1 = b1[1], h2 = b1[2], h3 = b1[3];
        #pragma unroll
        for (int i = 0; i < 8; ++i) {
            h0 += z[i] * w1[i];
            h1 += z[i] * w1[8 + i];
            h2 += z[i] * w1[16 + i];
            h3 += z[i] * w1[24 + i];
        }
        h0 = fmaxf(h0, 0.f); h1 = fmaxf(h1, 0.f);
        h2 = fmaxf(h2, 0.f); h3 = fmaxf(h3, 0.f);
        const float o = b2[ll] + h0 * w2[ll * 4 + 0] + h1 * w2[ll * 4 + 1]
                                + h2 * w2[ll * 4 + 2] + h3 * w2[ll * 4 + 3];
        out[(size_t)sample * 8 + ll] = o;
    }
}

extern "C" void kernel_launch(void* const* d_in, const int* in_sizes, int n_in,
                              void* d_out, int out_size, void* d_ws, size_t ws_size,
                              hipStream_t stream)
{
    const float* x  = (const float*)d_in[0];
    const float* qw = (const float*)d_in[1];
    const float* w1 = (const float*)d_in[2];
    const float* b1 = (const float*)d_in[3];
    const float* w2 = (const float*)d_in[4];
    const float* b2 = (const float*)d_in[5];
    float* out = (float*)d_out;

    const int nsamp = in_sizes[0] / 8;              // 65536
    const int total_threads = nsamp * 16;           // 16 lanes per sample
    const int blocks = (total_threads + 255) / 256; // 4096

    hipLaunchKernelGGL(qae_fused, dim3(blocks), dim3(256), 0, stream,
                       x, qw, w1, b1, w2, b2, out, nsamp);
}